// Round 9
// baseline (300.009 us; speedup 1.0000x reference)
//
#include <hip/hip_runtime.h>
#include <math.h>

typedef unsigned short ushort_t;

constexpr int BB = 8, T1 = 2048, T2 = 2048, D = 256;
constexpr float MARGIN = 4e-3f;   // 3-limb bf16 score error ~1e-4; 40x headroom

// ---- workspace layout (fast path) ----
constexpr size_t OFF_QC    = 0;                         // int counter (16 B)
constexpr size_t OFF_QUEUE = 64;                        // 16384 ints
constexpr size_t OFF_S1P   = (size_t)2 << 20;           // packed bf16 hi/lo s1 (16.8 MB)
constexpr size_t SZ_PACK   = (size_t)BB * 128 * 8 * 2 * 64 * 16; // b*tile16*g*limb*lane*16B
constexpr size_t OFF_S2P   = OFF_S1P + SZ_PACK;
constexpr size_t WS_NEEDED = OFF_S2P + SZ_PACK;         // ~35.7 MB

typedef __attribute__((ext_vector_type(8))) __bf16 bf16x8;
typedef __attribute__((ext_vector_type(4))) float  f32x4;

__device__ __forceinline__ unsigned f2bf(float x) {
    unsigned u = __float_as_uint(x);
    return (u + 0x7fffu + ((u >> 16) & 1u)) >> 16;
}
__device__ __forceinline__ float bf2f(unsigned h) { return __uint_as_float(h << 16); }

// non-temporal (no-allocate) helpers: keep streaming traffic out of L2 so the
// 2.1 MB packed B slice stays resident per XCD (r9 theory).
__device__ __forceinline__ void nt_store4(float* p, float4 v) {
    __builtin_nontemporal_store(v.x, p);
    __builtin_nontemporal_store(v.y, p + 1);
    __builtin_nontemporal_store(v.z, p + 2);
    __builtin_nontemporal_store(v.w, p + 3);
}
__device__ __forceinline__ float4 nt_load4(const float* p) {
    float4 v;
    v.x = __builtin_nontemporal_load(p);
    v.y = __builtin_nontemporal_load(p + 1);
    v.z = __builtin_nontemporal_load(p + 2);
    v.w = __builtin_nontemporal_load(p + 3);
    return v;
}
__device__ __forceinline__ uint4 nt_load4u(const unsigned* p) {
    uint4 v;
    v.x = __builtin_nontemporal_load(p);
    v.y = __builtin_nontemporal_load(p + 1);
    v.z = __builtin_nontemporal_load(p + 2);
    v.w = __builtin_nontemporal_load(p + 3);
    return v;
}

// ============================================================================
// K0: convert fp32 -> bf16 hi/lo, packed in MFMA-fragment tile order.
// Tile = 16 rows x 32 k. Chunk (1 KB) = [lane 0..63][8 shorts],
// lane = (row&15) + 16*((k&31)>>3), element i -> k = (lane>>4)*8 + i.
// Flat: [b][tile16 (128)][g (8)][limb (2)][lane (64)][16 B].  (r4-verified)
// ============================================================================
__global__ __launch_bounds__(256) void k_convert(
    const float* __restrict__ s1, const float* __restrict__ s2,
    ushort_t* __restrict__ s1p, ushort_t* __restrict__ s2p)
{
    __shared__ __align__(16) ushort_t L[16384];   // 32 KB staging (2 tile16 of output)
    const int bx = blockIdx.x;
    const int tensor = bx >> 9, b = (bx >> 6) & 7, rt = bx & 63;  // rt: 32-row group
    const float* src = (tensor ? s2 : s1) + ((size_t)b * 2048 + rt * 32) * 256;
    ushort_t* dst = (tensor ? s2p : s1p) + (size_t)(b * 128 + rt * 2) * 8192;
    const int t = threadIdx.x;
#pragma unroll
    for (int i = 0; i < 8; ++i) {
        int f = i * 256 + t, rw = f >> 6, c4 = f & 63, k0 = c4 * 4;
        float4 v = *(const float4*)(src + rw * 256 + k0);
        unsigned hx = f2bf(v.x), hy = f2bf(v.y), hz = f2bf(v.z), hw = f2bf(v.w);
        ushort4 hi = make_ushort4((ushort_t)hx, (ushort_t)hy, (ushort_t)hz, (ushort_t)hw);
        ushort4 lo = make_ushort4((ushort_t)f2bf(v.x - bf2f(hx)), (ushort_t)f2bf(v.y - bf2f(hy)),
                                  (ushort_t)f2bf(v.z - bf2f(hz)), (ushort_t)f2bf(v.w - bf2f(hw)));
        int tile = rw >> 4, m = rw & 15, g = k0 >> 5;
        int lane = m + 16 * ((k0 >> 3) & 3), i0 = k0 & 7;
        int off = (tile * 8 + g) * 1024 + lane * 8 + i0;   // limb stride 512 shorts
        *(ushort4*)(&L[off])       = hi;
        *(ushort4*)(&L[off + 512]) = lo;
    }
    __syncthreads();
#pragma unroll
    for (int i = 0; i < 8; ++i) {
        int cidx = i * 256 + t;                             // 2048 x 16 B = 32 KB
        ((uint4*)dst)[cidx] = ((const uint4*)L)[cidx];      // normal stores: warm L2 for k_score
    }
}

// ============================================================================
// K1 (r9): r8 structure + non-temporal streaming. r8 post-mortem: one-hot
// stores write-allocate in L2, evicting the 2.1 MB packed B slice -> B reads
// fall to L3 (~537 MB @ ~12 TB/s ~= the 45 us stall). r9: nt (no-allocate)
// stores for one-hot/u, nt loads for A-staging & s2 gather; B loads cached.
// Grid 256 (1 block/CU), 512 thr (8 waves, 2/SIMD), wave owns a 256-j stream,
// B prefetch chains across jtb boundaries. A once to LDS; B read once/block.
// ============================================================================
__global__ __launch_bounds__(512, 2) void k_score_fused(
    const ushort_t* __restrict__ s1p, const ushort_t* __restrict__ s2p,
    const float* __restrict__ s2,
    float* __restrict__ u, float* __restrict__ oh,
    int* __restrict__ qcount, int* __restrict__ queue)
{
    __shared__ __align__(16) ushort_t AL[4 * 8192];   // 64 KB: 4 tile16 x (8g x 2limb x 1KB)
    __shared__ float4 mrg[64][8];
    __shared__ int    idxs[64];

    const int bx = blockIdx.x;
    const int b = bx & 7, rg = bx >> 3;               // 32 row-groups of 64
    const int r0 = rg * 64;
    const int t = threadIdx.x, w = t >> 6, l = t & 63;
    const int q = l >> 4, n = l & 15;

    // ---- stage A strip once (layout-preserving copy; nt loads: read-once) ----
    {
        const unsigned* src = (const unsigned*)(s1p + (size_t)(b * 128 + rg * 4) * 8192);
        uint4* dst = (uint4*)AL;
#pragma unroll
        for (int i = 0; i < 8; ++i) dst[i * 512 + t] = nt_load4u(src + (i * 512 + t) * 4);
    }
    mrg[t >> 3][t & 7] = make_float4(-INFINITY, -INFINITY, __int_as_float(0), 0.f);
    __syncthreads();

    // running top-2 per (rt, reg)  [row = rt*16 + q*4 + reg]
    float v1[4][4], v2[4][4]; int i1r[4][4];
#pragma unroll
    for (int rt = 0; rt < 4; ++rt)
#pragma unroll
        for (int r = 0; r < 4; ++r) { v1[rt][r] = -INFINITY; v2[rt][r] = -INFINITY; i1r[rt][r] = 0; }

    float* ohb = oh + ((size_t)b * T1 + r0) * T2;
    const float4 z4 = make_float4(0.f, 0.f, 0.f, 0.f);

    // wave's 16 tile16 (256 j), per-lane fragment base
    const ushort_t* Bw = s2p + (size_t)(b * 128 + w * 16) * 8192 + l * 8;

    f32x4 acc[4][4];                                   // [jj][rt]
    bf16x8 bF0[4][2], bF1[4][2];
#pragma unroll
    for (int jj = 0; jj < 4; ++jj) {                   // jtb=0, g=0 fragments
        bF0[jj][0] = *(const bf16x8*)(Bw + (size_t)jj * 8192);
        bF0[jj][1] = *(const bf16x8*)(Bw + (size_t)jj * 8192 + 512);
    }

#pragma unroll 1
    for (int jtb = 0; jtb < 4; ++jtb) {                // 4 x 4 tile16 = wave's 256 j
#pragma unroll
        for (int jj = 0; jj < 4; ++jj)
#pragma unroll
            for (int rt = 0; rt < 4; ++rt)
#pragma unroll
                for (int r = 0; r < 4; ++r) acc[jj][rt][r] = 0.f;

        const ushort_t* Bb = Bw + (size_t)jtb * 4 * 8192;

        auto g_body = [&](int g, const ushort_t* prefPtr,
                          bf16x8 (&bCur)[4][2], bf16x8 (&bNext)[4][2]) {
            if (prefPtr) {
#pragma unroll
                for (int jj = 0; jj < 4; ++jj) {
                    bNext[jj][0] = *(const bf16x8*)(prefPtr + (size_t)jj * 8192);
                    bNext[jj][1] = *(const bf16x8*)(prefPtr + (size_t)jj * 8192 + 512);
                }
            }
            bf16x8 aF[4][2];
#pragma unroll
            for (int rt = 0; rt < 4; ++rt) {
                aF[rt][0] = *(const bf16x8*)(&AL[(rt * 8 + g) * 1024 + l * 8]);
                aF[rt][1] = *(const bf16x8*)(&AL[(rt * 8 + g) * 1024 + 512 + l * 8]);
            }
#pragma unroll
            for (int jj = 0; jj < 4; ++jj)
#pragma unroll
                for (int rt = 0; rt < 4; ++rt) {
                    acc[jj][rt] = __builtin_amdgcn_mfma_f32_16x16x32_bf16(aF[rt][0], bCur[jj][0], acc[jj][rt], 0, 0, 0);
                    acc[jj][rt] = __builtin_amdgcn_mfma_f32_16x16x32_bf16(aF[rt][0], bCur[jj][1], acc[jj][rt], 0, 0, 0);
                    acc[jj][rt] = __builtin_amdgcn_mfma_f32_16x16x32_bf16(aF[rt][1], bCur[jj][0], acc[jj][rt], 0, 0, 0);
                }
        };

#pragma unroll 1
        for (int g2 = 0; g2 < 4; ++g2) {
            const int g0 = 2 * g2;
            g_body(g0, Bb + (g0 + 1) * 1024, bF0, bF1);
            const ushort_t* nxt =
                (g2 < 3)   ? Bb + (g0 + 2) * 1024 :
                (jtb < 3)  ? Bb + (size_t)4 * 8192 :      // next jtb, g=0
                             (const ushort_t*)nullptr;
            g_body(g0 + 1, nxt, bF1, bF0);
        }

        // fold this jtb's 64 j into running top-2 (j ascending across jtb, jj)
#pragma unroll
        for (int rt = 0; rt < 4; ++rt)
#pragma unroll
            for (int reg = 0; reg < 4; ++reg)
#pragma unroll
                for (int jj = 0; jj < 4; ++jj) {
                    float v = acc[jj][rt][reg];
                    int j = w * 256 + jtb * 64 + jj * 16 + n;
                    if (v > v1[rt][reg])      { v2[rt][reg] = v1[rt][reg]; v1[rt][reg] = v; i1r[rt][reg] = j; }
                    else if (v > v2[rt][reg]) { v2[rt][reg] = v; }
                }

        // progressive one-hot zero-fill (NON-TEMPORAL: keep B slice in L2);
        // the single 1.0 is written after the barrier below.
        {
            int jbase = w * 256 + jtb * 64;
#pragma unroll
            for (int i = 0; i < 16; ++i) {
                int row = i * 4 + (l >> 4);
                int c4  = l & 15;
                nt_store4(ohb + (size_t)row * T2 + jbase + c4 * 4, z4);
            }
        }
    }

    // reduce across the 16 column-lanes, publish per-wave (per-256-j) partials
#pragma unroll
    for (int rt = 0; rt < 4; ++rt)
#pragma unroll
        for (int reg = 0; reg < 4; ++reg) {
            float a1 = v1[rt][reg], a2 = v2[rt][reg]; int ai = i1r[rt][reg];
#pragma unroll
            for (int off = 1; off < 16; off <<= 1) {
                float b1 = __shfl_xor(a1, off);
                int   bi = __shfl_xor(ai, off);
                float b2 = __shfl_xor(a2, off);
                if (b1 > a1 || (b1 == a1 && bi < ai)) { a2 = fmaxf(a1, b2); a1 = b1; ai = bi; }
                else                                   { a2 = fmaxf(b1, a2); }
            }
            if (n == rt * 4 + reg)   // 4 lanes (q=0..3) active, distinct rows
                mrg[rt * 16 + q * 4 + reg][w] = make_float4(a1, a2, __int_as_float(ai), 0.f);
        }
    __syncthreads();

    if (t < 64) {                     // merge 8 wave partials (w ascending = j ascending)
        float4 p = mrg[t][0];
        float V1 = p.x, V2 = p.y; int I = __float_as_int(p.z);
#pragma unroll
        for (int h = 1; h < 8; ++h) {
            float4 c = mrg[t][h];
            int ci = __float_as_int(c.z);
            if (c.x > V1 || (c.x == V1 && ci < I)) { V2 = fmaxf(V1, c.y); V1 = c.x; I = ci; }
            else                                    { V2 = fmaxf(V2, c.x); }
        }
        idxs[t] = I;
        if ((V1 - V2) < MARGIN) {
            int pos = atomicAdd(qcount, 1);
            if (pos < 16384) queue[pos] = b * T1 + r0 + t;
        }
        __builtin_nontemporal_store(1.0f, &ohb[(size_t)t * T2 + I]);  // zeros drained at barrier
    }
    __syncthreads();

    // u gather: 64 rows x 64 float4, coalesced; nt both directions
    const float* s2b = s2 + (size_t)b * T2 * D;
    float* ub = u + ((size_t)b * T1 + r0) * D;
#pragma unroll
    for (int i = 0; i < 8; ++i) {
        int flat = i * 512 + t, row = flat >> 6, c4 = flat & 63;
        float4 v = nt_load4(s2b + (size_t)idxs[row] * D + c4 * 4);
        nt_store4(ub + (size_t)row * D + c4 * 4, v);
    }
}

// ============================================================================
// K3: exact float64 recompute for flagged (near-tie) rows.
// ============================================================================
__global__ __launch_bounds__(256) void k_fixup(
    const float* __restrict__ s1, const float* __restrict__ s2,
    float* __restrict__ u, float* __restrict__ oh,
    const int* __restrict__ qcount, const int* __restrict__ queue, int qcap)
{
    __shared__ double s1d[D];
    __shared__ double rv[256];
    __shared__ int    rj[256];
    int nq = *qcount;
    if (nq > qcap) nq = qcap;
    const int t = threadIdx.x;
    for (int qi = blockIdx.x; qi < nq; qi += gridDim.x) {
        int rg = queue[qi];
        int b = rg >> 11, i = rg & (T1 - 1);
        __syncthreads();
        s1d[t] = (double)s1[((size_t)b * T1 + i) * D + t];
        __syncthreads();
        double bv = -INFINITY; int bj = 0;
        for (int jj = 0; jj < T2 / 256; ++jj) {
            int j = t + jj * 256;
            const float* row = s2 + ((size_t)b * T2 + j) * D;
            double s = 0.0;
            for (int k = 0; k < D; ++k) s = fma((double)row[k], s1d[k], s);
            if (s > bv) { bv = s; bj = j; }
        }
        rv[t] = bv; rj[t] = bj;
        __syncthreads();
        for (int stride = 128; stride > 0; stride >>= 1) {
            if (t < stride) {
                double ov = rv[t + stride]; int oj = rj[t + stride];
                if (ov > rv[t] || (ov == rv[t] && oj < rj[t])) { rv[t] = ov; rj[t] = oj; }
            }
            __syncthreads();
        }
        int best = rj[0];
        float* ohrow = oh + ((size_t)b * T1 + i) * T2;
#pragma unroll
        for (int jj = 0; jj < T2 / 256; ++jj) {
            int j = t + jj * 256;
            ohrow[j] = (j == best) ? 1.f : 0.f;
        }
        u[((size_t)b * T1 + i) * D + t] = s2[((size_t)b * T2 + best) * D + t];
    }
}

// ============================================================================
// Fallback (ws too small): round-2 fused kernel, verified correct.
// ============================================================================
constexpr int FB_AST = 264, FB_BST = 72;

__global__ __launch_bounds__(512, 2) void k_score_fb(
    const float* __restrict__ s1, const float* __restrict__ s2,
    float* __restrict__ u, float* __restrict__ oh,
    int* __restrict__ qcount, int* __restrict__ queue, int qcap)
{
    __shared__ __align__(16) short Ah[64 * FB_AST];
    __shared__ __align__(16) short Al[64 * FB_AST];
    __shared__ __align__(16) short Bh[256 * FB_BST];
    __shared__ __align__(16) short Bl[256 * FB_BST];
    __shared__ float cv1[64][4], cv2[64][4];
    __shared__ int   ci1[64][4], idx_s[64];

    const int bx = blockIdx.x;
    const int b  = bx & 7;
    const int r0 = (bx >> 3) * 64;
    const float* s1b = s1 + ((size_t)b * T1 + r0) * D;
    const float* s2b = s2 + (size_t)b * T2 * D;

    const int t = threadIdx.x;
    const int w = t >> 6, l = t & 63, q = l >> 4, ln = l & 15;
    const int rh = w >> 2;
    const int jq = w & 3;

    float4 pa[8];
#pragma unroll
    for (int i = 0; i < 8; ++i) {
        int flat = i * 512 + t, row = flat >> 6, f4 = flat & 63;
        pa[i] = *(const float4*)(s1b + row * D + f4 * 4);
    }
    float4 pb[8];
#pragma unroll
    for (int i = 0; i < 8; ++i) {
        int flat = i * 512 + t, jrow = flat >> 4, f4 = flat & 15;
        pb[i] = *(const float4*)(s2b + (size_t)jrow * D + f4 * 4);
    }
#pragma unroll
    for (int i = 0; i < 8; ++i) {
        int flat = i * 512 + t, row = flat >> 6, f4 = flat & 63;
        float4 v = pa[i];
        unsigned hx = f2bf(v.x), hy = f2bf(v.y), hz = f2bf(v.z), hw = f2bf(v.w);
        uint2 hh, ll;
        hh.x = hx | (hy << 16); hh.y = hz | (hw << 16);
        ll.x = f2bf(v.x - bf2f(hx)) | (f2bf(v.y - bf2f(hy)) << 16);
        ll.y = f2bf(v.z - bf2f(hz)) | (f2bf(v.w - bf2f(hw)) << 16);
        *(uint2*)(&Ah[row * FB_AST + f4 * 4]) = hh;
        *(uint2*)(&Al[row * FB_AST + f4 * 4]) = ll;
    }

    float v1[2][4], v2[2][4]; int i1[2][4];
#pragma unroll
    for (int rt = 0; rt < 2; ++rt)
#pragma unroll
        for (int r = 0; r < 4; ++r) { v1[rt][r] = -INFINITY; v2[rt][r] = -INFINITY; i1[rt][r] = 0; }

    f32x4 acc[2][4];

    for (int c = 0; c < 32; ++c) {
        const int iter = c >> 2, kc = c & 3;
        if (kc == 0) {
#pragma unroll
            for (int rt = 0; rt < 2; ++rt)
#pragma unroll
                for (int jt = 0; jt < 4; ++jt)
#pragma unroll
                    for (int r = 0; r < 4; ++r) acc[rt][jt][r] = 0.f;
        }
        __syncthreads();
#pragma unroll
        for (int i = 0; i < 8; ++i) {
            int flat = i * 512 + t, jrow = flat >> 4, f4 = flat & 15;
            float4 v = pb[i];
            unsigned hx = f2bf(v.x), hy = f2bf(v.y), hz = f2bf(v.z), hw = f2bf(v.w);
            uint2 hh, ll;
            hh.x = hx | (hy << 16); hh.y = hz | (hw << 16);
            ll.x = f2bf(v.x - bf2f(hx)) | (f2bf(v.y - bf2f(hy)) << 16);
            ll.y = f2bf(v.z - bf2f(hz)) | (f2bf(v.w - bf2f(hw)) << 16);
            *(uint2*)(&Bh[jrow * FB_BST + f4 * 4]) = hh;
            *(uint2*)(&Bl[jrow * FB_BST + f4 * 4]) = ll;
        }
        if (c < 31) {
            int c2 = c + 1, it2 = c2 >> 2, kc2 = c2 & 3;
#pragma unroll
            for (int i = 0; i < 8; ++i) {
                int flat = i * 512 + t, jrow = flat >> 4, f4 = flat & 15;
                pb[i] = *(const float4*)(s2b + (size_t)(it2 * 256 + jrow) * D + kc2 * 64 + f4 * 4);
            }
        }
        __syncthreads();

#pragma unroll
        for (int ks = 0; ks < 2; ++ks) {
            const int kA = kc * 64 + ks * 32 + q * 8;
            bf16x8 ah[2], al8[2];
#pragma unroll
            for (int rt = 0; rt < 2; ++rt) {
                int off = (rh * 32 + rt * 16 + ln) * FB_AST + kA;
                ah[rt]  = *(const bf16x8*)(&Ah[off]);
                al8[rt] = *(const bf16x8*)(&Al[off]);
            }
#pragma unroll
            for (int jt = 0; jt < 4; ++jt) {
                int boff = (jq * 64 + jt * 16 + ln) * FB_BST + ks * 32 + q * 8;
                bf16x8 bh = *(const bf16x8*)(&Bh[boff]);
                bf16x8 bl = *(const bf16x8*)(&Bl[boff]);
#pragma unroll
                for (int rt = 0; rt < 2; ++rt) {
                    acc[rt][jt] = __builtin_amdgcn_mfma_f32_16x16x32_bf16(ah[rt],  bh, acc[rt][jt], 0, 0, 0);
                    acc[rt][jt] = __builtin_amdgcn_mfma_f32_16x16x32_bf16(ah[rt],  bl, acc[rt][jt], 0, 0, 0);
                    acc[rt][jt] = __builtin_amdgcn_mfma_f32_16x16x32_bf16(al8[rt], bh, acc[rt][jt], 0, 0, 0);
                }
            }
        }

        if (kc == 3) {
#pragma unroll
            for (int rt = 0; rt < 2; ++rt)
#pragma unroll
                for (int jt = 0; jt < 4; ++jt)
#pragma unroll
                    for (int r = 0; r < 4; ++r) {
                        float val = acc[rt][jt][r];
                        int j = iter * 256 + jq * 64 + jt * 16 + ln;
                        if (val > v1[rt][r]) { v2[rt][r] = v1[rt][r]; v1[rt][r] = val; i1[rt][r] = j; }
                        else if (val > v2[rt][r]) v2[rt][r] = val;
                    }
        }
    }

#pragma unroll
    for (int rt = 0; rt < 2; ++rt)
#pragma unroll
        for (int r = 0; r < 4; ++r) {
            float a1 = v1[rt][r], a2 = v2[rt][r]; int ai = i1[rt][r];
#pragma unroll
            for (int off = 1; off < 16; off <<= 1) {
                float b1 = __shfl_xor(a1, off);
                int   bi = __shfl_xor(ai, off);
                float b2 = __shfl_xor(a2, off);
                if (b1 > a1 || (b1 == a1 && bi < ai)) { a2 = fmaxf(a1, b2); a1 = b1; ai = bi; }
                else                                   { a2 = fmaxf(b1, a2); }
            }
            if (ln == 0) {
                int row = rh * 32 + rt * 16 + q * 4 + r;
                cv1[row][jq] = a1; cv2[row][jq] = a2; ci1[row][jq] = ai;
            }
        }
    __syncthreads();

    if (t < 64) {
        float V1 = cv1[t][0], V2 = cv2[t][0]; int I = ci1[t][0];
#pragma unroll
        for (int h = 1; h < 4; ++h) {
            float c1 = cv1[t][h], c2 = cv2[t][h]; int ci = ci1[t][h];
            if (c1 > V1 || (c1 == V1 && ci < I)) { V2 = fmaxf(V1, c2); V1 = c1; I = ci; }
            else                                  { V2 = fmaxf(V2, c1); }
        }
        idx_s[t] = I;
        if (qcap > 0 && (V1 - V2) < MARGIN) {
            int pos = atomicAdd(qcount, 1);
            if (pos < qcap) queue[pos] = b * T1 + r0 + t;
        }
    }
    __syncthreads();

    float* ub = u + ((size_t)b * T1 + r0) * D;
#pragma unroll
    for (int i = 0; i < 8; ++i) {
        int flat = i * 512 + t, row = flat >> 6, f4 = flat & 63;
        float4 v = *(const float4*)(s2b + (size_t)idx_s[row] * D + f4 * 4);
        *(float4*)(ub + (size_t)row * D + f4 * 4) = v;
    }
    float* ohb = oh + ((size_t)b * T1 + r0) * T2;
#pragma unroll 4
    for (int i = 0; i < 64; ++i) {
        int flat = i * 512 + t, row = flat >> 9, f4 = flat & 511;
        int base = f4 * 4, id = idx_s[row];
        float4 vv;
        vv.x = (base     == id) ? 1.f : 0.f;
        vv.y = (base + 1 == id) ? 1.f : 0.f;
        vv.z = (base + 2 == id) ? 1.f : 0.f;
        vv.w = (base + 3 == id) ? 1.f : 0.f;
        *(float4*)(ohb + (size_t)row * T2 + base) = vv;
    }
}

extern "C" void kernel_launch(void* const* d_in, const int* in_sizes, int n_in,
                              void* d_out, int out_size, void* d_ws, size_t ws_size,
                              hipStream_t stream)
{
    const float* s1 = (const float*)d_in[0];
    const float* s2 = (const float*)d_in[1];
    float* u  = (float*)d_out;                       // [8,2048,256]
    float* oh = u + (size_t)BB * T1 * D;             // [8,2048,2048]
    char* ws = (char*)d_ws;

    if (ws_size >= WS_NEEDED) {
        int*      qc    = (int*)(ws + OFF_QC);
        int*      queue = (int*)(ws + OFF_QUEUE);
        ushort_t* s1p   = (ushort_t*)(ws + OFF_S1P);
        ushort_t* s2p   = (ushort_t*)(ws + OFF_S2P);
        hipMemsetAsync(ws + OFF_QC, 0, 16, stream);
        k_convert<<<dim3(1024), dim3(256), 0, stream>>>(s1, s2, s1p, s2p);
        k_score_fused<<<dim3(256), dim3(512), 0, stream>>>(s1p, s2p, s2, u, oh, qc, queue);
        k_fixup<<<dim3(128), dim3(256), 0, stream>>>(s1, s2, u, oh, qc, queue, 16384);
    } else {
        int  qcap   = 0;
        int* qcount = nullptr;
        int* queue  = nullptr;
        if (ws_size >= 256) {
            qcount = (int*)d_ws;
            queue  = (int*)d_ws + 4;
            size_t cap = (ws_size - 16) / sizeof(int);
            qcap = (int)(cap > (size_t)(BB * T1) ? (size_t)(BB * T1) : cap);
            hipMemsetAsync(d_ws, 0, 16, stream);
        }
        k_score_fb<<<dim3(BB * (T1 / 64)), dim3(512), 0, stream>>>(
            s1, s2, u, oh, qcount, queue, qcap);
        if (qcap > 0)
            k_fixup<<<dim3(64), dim3(256), 0, stream>>>(
                s1, s2, u, oh, qcount, queue, qcap);
    }
}